// Round 6
// baseline (401.882 us; speedup 1.0000x reference)
//
#include <hip/hip_runtime.h>
#include <cstddef>
#include <cstdint>

// Problem constants
#define B_TOT   256
#define IN_CAPS 1152
#define KD      8
#define NJ      10
#define ND      16
#define JD      160            // NJ*ND

typedef __bf16 v8bf  __attribute__((ext_vector_type(8)));
typedef float  v16f  __attribute__((ext_vector_type(16)));

__device__ __forceinline__ float b2f_hi(uint32_t w)  { return __uint_as_float(w & 0xffff0000u); }
__device__ __forceinline__ float b2f_lo(uint32_t w)  { return __uint_as_float(w << 16); }
__device__ __forceinline__ unsigned short f2bs(float f) {
    __bf16 b = (__bf16)f;                     // RNE
    return __builtin_bit_cast(unsigned short, b);
}

// ---------------------------------------------------------------------------
// W_t[i][jd][k] bf16  (jd = j*16+d, k contiguous) — B-operand-friendly layout.
// Reads coalesced per k (consecutive d threads), writes dwordx4 coalesced.
__global__ __launch_bounds__(256)
void wt_build(const float* __restrict__ W, unsigned short* __restrict__ Wt)
{
    const int id = blockIdx.x * 256 + threadIdx.x;       // < 1152*160
    const int i  = id / JD;
    const int jd = id - i * JD;
    const int j = jd >> 4, d = jd & 15;
    const float* src = W + ((size_t)(i * NJ + j) * KD) * ND + d;
    unsigned int pk[4];
    #pragma unroll
    for (int kk = 0; kk < 4; ++kk) {
        const unsigned short lo = f2bs(src[(2 * kk + 0) * ND]);
        const unsigned short hi = f2bs(src[(2 * kk + 1) * ND]);
        pk[kk] = (unsigned)lo | ((unsigned)hi << 16);
    }
    *(uint4*)(Wt + (size_t)id * KD) = make_uint4(pk[0], pk[1], pk[2], pk[3]);
}

// ---------------------------------------------------------------------------
// u_hat producer: per (wave,i): 5x mfma_f32_32x32x16_bf16 (K=8 of 16 used;
// upper-k half-lanes zeroed on BOTH A and B so any within-lane k order cancels).
// C/D layout (measured m74/m101): col=lane&31, row=(reg&3)+8*(reg>>2)+4*(lane>>5).
// Output rows [bh][i][160] bf16 via per-wave LDS transpose (contiguous 320B rows).
// s1 = sum_i u_hat accumulated in regs -> LDS -> per-block partial slice.
__global__ __launch_bounds__(256)
void uhat_kernel(const float* __restrict__ x, const unsigned short* __restrict__ Wt,
                 unsigned short* __restrict__ u, float* __restrict__ s1p,
                 int b_base, int NB)
{
    const int ic  = blockIdx.x;            // 0..71 (16 i each)
    const int bt  = blockIdx.y;            // 0..NB/32-1
    const int b0h = bt * 32;

    const int tid  = threadIdx.x;
    const int wv   = tid >> 6;
    const int lane = tid & 63;
    const int mN   = lane & 31;            // A row / B col / C col
    const int half = lane >> 5;            // k-half selector

    __shared__ unsigned short u_lds[4][32][168];   // 43008 B (168: bank pad)
    __shared__ float s1_lds[32 * JD];              // 20480 B

    for (int e = tid; e < 32 * JD; e += 256) s1_lds[e] = 0.f;
    __syncthreads();

    const v16f czero = {0.f,0.f,0.f,0.f, 0.f,0.f,0.f,0.f,
                        0.f,0.f,0.f,0.f, 0.f,0.f,0.f,0.f};
    const v8bf zfrag = {(__bf16)0.f,(__bf16)0.f,(__bf16)0.f,(__bf16)0.f,
                        (__bf16)0.f,(__bf16)0.f,(__bf16)0.f,(__bf16)0.f};
    v16f acc[5];
    #pragma unroll
    for (int t = 0; t < 5; ++t) acc[t] = czero;

    const v8bf* WtV = (const v8bf*)Wt;

    for (int q = 0; q < 4; ++q) {
        const int i = ic * 16 + wv * 4 + q;

        v8bf a = zfrag;
        if (half == 0) {                    // lanes 0..31 hold k=0..7 (real K)
            const float4* xp = (const float4*)(x +
                ((size_t)(b_base + b0h + mN) * IN_CAPS + i) * KD);
            const float4 x0 = xp[0], x1 = xp[1];
            a[0]=(__bf16)x0.x; a[1]=(__bf16)x0.y; a[2]=(__bf16)x0.z; a[3]=(__bf16)x0.w;
            a[4]=(__bf16)x1.x; a[5]=(__bf16)x1.y; a[6]=(__bf16)x1.z; a[7]=(__bf16)x1.w;
        }

        #pragma unroll
        for (int t = 0; t < 5; ++t) {
            v8bf b = zfrag;
            if (half == 0) b = WtV[(size_t)i * JD + t * 32 + mN];
            const v16f dd = __builtin_amdgcn_mfma_f32_32x32x16_bf16(a, b, czero, 0, 0, 0);
            acc[t] = acc[t] + dd;
            #pragma unroll
            for (int r = 0; r < 16; ++r) {
                const int mm = (r & 3) + 8 * (r >> 2) + 4 * half;
                u_lds[wv][mm][t * 32 + mN] = f2bs(dd[r]);
            }
        }

        // wave-private readback: 640 dwordx4 units (32 rows x 320 B), store rows
        #pragma unroll
        for (int qq = 0; qq < 10; ++qq) {
            const int f   = qq * 64 + lane;
            const int mm  = f / 20;
            const int c16 = f - mm * 20;
            const uint4 vls = *(const uint4*)&u_lds[wv][mm][c16 * 8];
            *(uint4*)(u + ((size_t)(b0h + mm) * IN_CAPS + i) * JD + c16 * 8) = vls;
        }
    }

    // merge per-wave s1 accumulators
    #pragma unroll
    for (int t = 0; t < 5; ++t)
        #pragma unroll
        for (int r = 0; r < 16; ++r) {
            const int mm = (r & 3) + 8 * (r >> 2) + 4 * half;
            atomicAdd(&s1_lds[mm * JD + t * 32 + mN], acc[t][r]);
        }
    __syncthreads();
    for (int e = tid; e < 32 * JD; e += 256) {
        const int mm = e / JD, col = e - mm * JD;
        s1p[((size_t)ic * NB + b0h + mm) * JD + col] = s1_lds[e];
    }
}

// ---------------------------------------------------------------------------
// Routing pass: stream u_hat rows, wave-local softmax (lane = jl*4+dq, jl<10
// active), zero barriers, per-(isp,b) partial s written by a unique wave.
__global__ __launch_bounds__(512)
void route_kernel(const unsigned short* __restrict__ u, const float* __restrict__ vin,
                  float* __restrict__ spart, int NB)
{
    const int isp = blockIdx.x;            // 0..31 (36 i each)
    const int bg  = blockIdx.y;            // 0..NB/16-1
    const int wv   = threadIdx.x >> 6;
    const int lane = threadIdx.x & 63;
    const bool act = lane < 40;            // jl = lane>>2 < 10
    const int i0 = isp * 36;

    #pragma unroll
    for (int bb = 0; bb < 2; ++bb) {
        const int bh = bg * 16 + wv * 2 + bb;
        float4 vs = make_float4(0.f, 0.f, 0.f, 0.f);
        if (act) vs = *(const float4*)(vin + (size_t)bh * JD + lane * 4);
        float4 acc = make_float4(0.f, 0.f, 0.f, 0.f);
        const unsigned short* up = u + ((size_t)bh * IN_CAPS + i0) * JD + lane * 4;
        #pragma unroll 4
        for (int ii = 0; ii < 36; ++ii) {
            uint2 raw = make_uint2(0u, 0u);
            if (act) raw = *(const uint2*)(up + (size_t)ii * JD);
            float4 uu;
            uu.x = b2f_lo(raw.x); uu.y = b2f_hi(raw.x);
            uu.z = b2f_lo(raw.y); uu.w = b2f_hi(raw.y);
            float lg = uu.x*vs.x + uu.y*vs.y + uu.z*vs.z + uu.w*vs.w;
            lg += __shfl_xor(lg, 1); lg += __shfl_xor(lg, 2);     // sum over d-quad
            const float e = act ? __expf(lg) : 0.f;               // |logit| small
            float den = e;
            den += __shfl_xor(den, 4);  den += __shfl_xor(den, 8);
            den += __shfl_xor(den, 16); den += __shfl_xor(den, 32);
            const float cc = __fdividef(e, den);
            acc.x += cc * uu.x; acc.y += cc * uu.y;
            acc.z += cc * uu.z; acc.w += cc * uu.w;
        }
        if (act) *(float4*)(spart + ((size_t)isp * NB + bh) * JD + lane * 4) = acc;
    }
}

// ---------------------------------------------------------------------------
// Reduce NS partial slices, optional premul, squash, optional add of vprev.
template<int NS>
__global__ __launch_bounds__(256)
void vred_kernel(const float* __restrict__ sp, const float* __restrict__ vprev,
                 float* __restrict__ vout, float premul, int NB)
{
    const int idx = blockIdx.x * 256 + threadIdx.x;   // < NB*JD
    float s = 0.f;
    #pragma unroll
    for (int p = 0; p < NS; ++p) s += sp[(size_t)p * NB * JD + idx];
    s *= premul;
    float sq = s * s;
    sq += __shfl_xor(sq, 1); sq += __shfl_xor(sq, 2);
    sq += __shfl_xor(sq, 4); sq += __shfl_xor(sq, 8);       // norm over 16 d
    float v = s * (sq / (1.f + sq) / sqrtf(sq + 1e-7f));
    if (vprev) v += vprev[idx];
    vout[idx] = v;
}

// ===========================================================================
// Legacy fallback (R5 path) — used only if ws is too small for the MFMA path.
#define L_BB      4
#define L_ISPLIT  8
#define L_IRANGE  (IN_CAPS/L_ISPLIT)
#define L_NWAVES  12
#define L_NT      (L_NWAVES*64)
#define L_CHUNK   (L_NWAVES*2)
#define L_NCHUNK  (L_IRANGE/L_CHUNK)
#define L_GRID    ((B_TOT/L_BB)*L_ISPLIT)

__device__ __forceinline__ float l_dot4(float4 a, float4 b) {
    return a.x*b.x + a.y*b.y + a.z*b.z + a.w*b.w;
}
__device__ __forceinline__ float l_getc(const float4& v, int k) {
    switch (k) { case 0: return v.x; case 1: return v.y; case 2: return v.z; default: return v.w; }
}

template<int NSRC, bool PARTIAL>
__global__ __launch_bounds__(L_NT)
void legacy_iter(const float* __restrict__ x, const float* __restrict__ Wt,
                 const float* __restrict__ sA, const float* __restrict__ sB,
                 float* __restrict__ s_out)
{
    constexpr int PART = PARTIAL ? L_ISPLIT : 1;
    const int isp = blockIdx.x & (L_ISPLIT - 1);
    const int g   = blockIdx.x >> 3;
    const int b0  = g * L_BB;
    const int i_begin = isp * L_IRANGE;
    const int t = threadIdx.x, wv = t >> 6, lane = t & 63;
    const int jl = lane >> 2, dq = lane & 3;
    const bool act = (jl < NJ);

    __shared__ float4 x_lds[L_BB * L_IRANGE * 2];
    __shared__ float  s_red[L_BB * JD];

    for (int f = t; f < L_BB * L_IRANGE * 2; f += L_NT) {
        const int bb = f / (L_IRANGE * 2);
        const int fi = f - bb * (L_IRANGE * 2);
        x_lds[f] = ((const float4*)(x + ((size_t)(b0 + bb) * IN_CAPS + i_begin) * KD))[fi];
    }
    if (t < L_BB * JD) s_red[t] = 0.f;

    float4 vs[L_BB];
    #pragma unroll
    for (int bb = 0; bb < L_BB; ++bb) vs[bb] = make_float4(0.f, 0.f, 0.f, 0.f);
    if (NSRC >= 1 && act) {
        #pragma unroll
        for (int bb = 0; bb < L_BB; ++bb) {
            float4 a = make_float4(0.f, 0.f, 0.f, 0.f);
            #pragma unroll
            for (int p = 0; p < PART; ++p) {
                const float4 q = *(const float4*)(sA + ((size_t)p * B_TOT + b0 + bb) * JD + jl * ND + dq * 4);
                a.x += q.x; a.y += q.y; a.z += q.z; a.w += q.w;
            }
            float n = l_dot4(a, a);
            n += __shfl_xor(n, 1); n += __shfl_xor(n, 2);
            const float sc = n / (1.f + n) / sqrtf(n + 1e-7f);
            vs[bb].x = a.x * sc; vs[bb].y = a.y * sc; vs[bb].z = a.z * sc; vs[bb].w = a.w * sc;
            if (NSRC == 2) {
                float4 b = make_float4(0.f, 0.f, 0.f, 0.f);
                #pragma unroll
                for (int p = 0; p < PART; ++p) {
                    const float4 q = *(const float4*)(sB + ((size_t)p * B_TOT + b0 + bb) * JD + jl * ND + dq * 4);
                    b.x += q.x; b.y += q.y; b.z += q.z; b.w += q.w;
                }
                float n2 = l_dot4(b, b);
                n2 += __shfl_xor(n2, 1); n2 += __shfl_xor(n2, 2);
                const float sc2 = n2 / (1.f + n2) / sqrtf(n2 + 1e-7f);
                vs[bb].x += b.x * sc2; vs[bb].y += b.y * sc2;
                vs[bb].z += b.z * sc2; vs[bb].w += b.w * sc2;
            }
        }
    }
    __syncthreads();

    float4 s_acc[L_BB];
    #pragma unroll
    for (int bb = 0; bb < L_BB; ++bb) s_acc[bb] = make_float4(0.f, 0.f, 0.f, 0.f);
    const float4* Wf4 = (const float4*)Wt;

    for (int c = 0; c < L_NCHUNK; ++c) {
        #pragma unroll
        for (int ii = 0; ii < 2; ++ii) {
            const int i_loc = c * L_CHUNK + wv * 2 + ii;
            float4 u[L_BB];
            #pragma unroll
            for (int bb = 0; bb < L_BB; ++bb) u[bb] = make_float4(0.f, 0.f, 0.f, 0.f);
            if (act) {
                const float4* wp = Wf4 + ((size_t)(i_begin + i_loc) * NJ + jl) * 32 + dq;
                float4 w[8];
                #pragma unroll
                for (int k = 0; k < 8; ++k) w[k] = wp[k * 4];
                #pragma unroll
                for (int bb = 0; bb < L_BB; ++bb) {
                    const float4 xk0 = x_lds[(bb * L_IRANGE + i_loc) * 2 + 0];
                    const float4 xk1 = x_lds[(bb * L_IRANGE + i_loc) * 2 + 1];
                    #pragma unroll
                    for (int k = 0; k < 4; ++k) {
                        const float xs = l_getc(xk0, k);
                        u[bb].x += xs * w[k].x; u[bb].y += xs * w[k].y;
                        u[bb].z += xs * w[k].z; u[bb].w += xs * w[k].w;
                    }
                    #pragma unroll
                    for (int k = 0; k < 4; ++k) {
                        const float xs = l_getc(xk1, k);
                        u[bb].x += xs * w[4+k].x; u[bb].y += xs * w[4+k].y;
                        u[bb].z += xs * w[4+k].z; u[bb].w += xs * w[4+k].w;
                    }
                }
            }
            if (NSRC == 0) {
                #pragma unroll
                for (int bb = 0; bb < L_BB; ++bb) {
                    s_acc[bb].x += u[bb].x; s_acc[bb].y += u[bb].y;
                    s_acc[bb].z += u[bb].z; s_acc[bb].w += u[bb].w;
                }
            } else {
                #pragma unroll
                for (int bb = 0; bb < L_BB; ++bb) {
                    float lg = l_dot4(u[bb], vs[bb]);
                    lg += __shfl_xor(lg, 1); lg += __shfl_xor(lg, 2);
                    const float e = act ? __expf(lg) : 0.f;
                    float den = e;
                    den += __shfl_xor(den, 4);  den += __shfl_xor(den, 8);
                    den += __shfl_xor(den, 16); den += __shfl_xor(den, 32);
                    const float cc = e / den;
                    s_acc[bb].x += cc * u[bb].x; s_acc[bb].y += cc * u[bb].y;
                    s_acc[bb].z += cc * u[bb].z; s_acc[bb].w += cc * u[bb].w;
                }
            }
        }
    }

    const float premul = (NSRC == 0) ? 0.1f : 1.0f;
    if (act) {
        #pragma unroll
        for (int bb = 0; bb < L_BB; ++bb) {
            float* dst = &s_red[bb * JD + jl * ND + dq * 4];
            atomicAdd(dst + 0, s_acc[bb].x * premul);
            atomicAdd(dst + 1, s_acc[bb].y * premul);
            atomicAdd(dst + 2, s_acc[bb].z * premul);
            atomicAdd(dst + 3, s_acc[bb].w * premul);
        }
    }
    __syncthreads();
    if (t < L_BB * JD) {
        const int bb = t / JD, jd = t - bb * JD;
        const float val = s_red[t];
        if (PARTIAL)
            s_out[((size_t)isp * B_TOT + b0 + bb) * JD + jd] = val;
        else
            unsafeAtomicAdd(&s_out[(size_t)(b0 + bb) * JD + jd], val);
    }
}

template<int P>
__global__ __launch_bounds__(256)
void legacy_squash(const float* __restrict__ s, float* __restrict__ out)
{
    const int idx = blockIdx.x * 256 + threadIdx.x;
    float sv = 0.f;
    #pragma unroll
    for (int p = 0; p < P; ++p) sv += s[(size_t)p * B_TOT * JD + idx];
    float sq = sv * sv;
    sq += __shfl_xor(sq, 1); sq += __shfl_xor(sq, 2);
    sq += __shfl_xor(sq, 4); sq += __shfl_xor(sq, 8);
    const float scale = sq / (1.f + sq) / sqrtf(sq + 1e-7f);
    out[idx] = sv * scale;
}

// ===========================================================================
extern "C" void kernel_launch(void* const* d_in, const int* in_sizes, int n_in,
                              void* d_out, int out_size, void* d_ws, size_t ws_size,
                              hipStream_t stream)
{
    const float* x = (const float*)d_in[0];    // [256,1152,8]
    const float* W = (const float*)d_in[1];    // [1152,10,8,16]
    float* out = (float*)d_out;                // [256,10,16]

    const size_t wt_bytes = (size_t)IN_CAPS * JD * KD * 2;          // 2.95 MB
    auto need = [&](int NB) -> size_t {
        return wt_bytes
             + (size_t)NB * IN_CAPS * JD * 2        // u_hat bf16
             + (size_t)72 * NB * JD * 4             // s1 partials
             + (size_t)32 * NB * JD * 4 * 2         // s2,s3 partials
             + (size_t)NB * JD * 4 * 2;             // v1, v12
    };

    int NB = 0;
    if      (ws_size >= need(128)) NB = 128;
    else if (ws_size >= need(64))  NB = 64;
    else if (ws_size >= need(32))  NB = 32;

    if (NB > 0) {
        char* p = (char*)d_ws;
        unsigned short* Wt = (unsigned short*)p;  p += wt_bytes;
        unsigned short* u  = (unsigned short*)p;  p += (size_t)NB * IN_CAPS * JD * 2;
        float* s1p = (float*)p;                   p += (size_t)72 * NB * JD * 4;
        float* s2p = (float*)p;                   p += (size_t)32 * NB * JD * 4;
        float* s3p = (float*)p;                   p += (size_t)32 * NB * JD * 4;
        float* v1  = (float*)p;                   p += (size_t)NB * JD * 4;
        float* v12 = (float*)p;

        wt_build<<<dim3(IN_CAPS * JD / 256), dim3(256), 0, stream>>>(W, Wt);

        const int passes = B_TOT / NB;
        const int vgrid  = NB * JD / 256;
        for (int ps = 0; ps < passes; ++ps) {
            const int b_base = ps * NB;
            uhat_kernel<<<dim3(72, NB / 32), dim3(256), 0, stream>>>(x, Wt, u, s1p, b_base, NB);
            vred_kernel<72><<<dim3(vgrid), dim3(256), 0, stream>>>(s1p, nullptr, v1, 0.1f, NB);
            route_kernel<<<dim3(32, NB / 16), dim3(512), 0, stream>>>(u, v1, s2p, NB);
            vred_kernel<32><<<dim3(vgrid), dim3(256), 0, stream>>>(s2p, v1, v12, 1.0f, NB);
            route_kernel<<<dim3(32, NB / 16), dim3(512), 0, stream>>>(u, v12, s3p, NB);
            vred_kernel<32><<<dim3(vgrid), dim3(256), 0, stream>>>(s3p, nullptr,
                                                                   out + (size_t)b_base * JD, 1.0f, NB);
        }
        return;
    }

    // ------- legacy fallback (ws too small for materialized u_hat) -------
    dim3 grid(L_GRID), blk(L_NT);
    dim3 sgrid((B_TOT * JD) / 256), sblk(256);
    const size_t slice = (size_t)B_TOT * JD;
    const size_t psz   = (size_t)L_ISPLIT * slice;

    if (ws_size >= 3 * psz * sizeof(float)) {
        float* sA = (float*)d_ws;
        float* sB = sA + psz;
        float* sC = sB + psz;
        legacy_iter<0, true><<<grid, blk, 0, stream>>>(x, W, nullptr, nullptr, sA);
        legacy_iter<1, true><<<grid, blk, 0, stream>>>(x, W, sA, nullptr, sB);
        legacy_iter<2, true><<<grid, blk, 0, stream>>>(x, W, sA, sB, sC);
        legacy_squash<L_ISPLIT><<<sgrid, sblk, 0, stream>>>(sC, out);
    } else {
        float* sA = (float*)d_ws;
        float* sB = sA + slice;
        float* sC = sB + slice;
        hipMemsetAsync(d_ws, 0, 3 * slice * sizeof(float), stream);
        legacy_iter<0, false><<<grid, blk, 0, stream>>>(x, W, nullptr, nullptr, sA);
        legacy_iter<1, false><<<grid, blk, 0, stream>>>(x, W, sA, nullptr, sB);
        legacy_iter<2, false><<<grid, blk, 0, stream>>>(x, W, sA, sB, sC);
        legacy_squash<1><<<sgrid, sblk, 0, stream>>>(sC, out);
    }
}